// Round 1
// baseline (101.525 us; speedup 1.0000x reference)
//
#include <hip/hip_runtime.h>
#include <hip/hip_bf16.h>
#include <math.h>

// GaussianModel histogram splat:
//   out[b] = sum_i inten_i * clip( (coeff_i*pdf1 + (1-coeff_i)*pdf2) * BIN_RES/2, 0, 1 ) / r_b^2
// Upper clip at 1.0 is provably inactive (sigma >= BIN_RES/2 => pdf*BIN_RES/2 <= 0.607),
// so intensity folds into per-point constants and __saturatef is exact.

#define NBINS 512
#define CHUNK 256
#define K_SQRT_HALF_PI 0.3989422804014327f   // sqrt(0.5/pi)
#define LOG2E 1.4426950408889634f

#if __has_builtin(__builtin_amdgcn_exp2f)
#define FAST_EXP2(x) __builtin_amdgcn_exp2f(x)
#else
#define FAST_EXP2(x) __expf((x) * 0.6931471805599453f)
#endif

__global__ __launch_bounds__(NBINS) void gauss_hist(
    const float* __restrict__ means,
    const float* __restrict__ scan_point,
    const float* __restrict__ colours,
    const float* __restrict__ coeffs,
    const float* __restrict__ opac,
    const float* __restrict__ scales,
    const int* __restrict__ view_id,
    float* __restrict__ out,
    int n)
{
    __shared__ float4 s_pt[CHUNK];   // {r0, c2 = -0.5*log2e/sigma^2, a, b}
    const int t = threadIdx.x;
    const int base = blockIdx.x * CHUNK;

    // --- stage one 256-point chunk: per-point precompute into LDS ---
    if (t < CHUNK) {
        const int p = base + t;
        float4 v = make_float4(0.f, 0.f, 0.f, 0.f);  // inert: exp2(0)=1, a=b=0 -> contribution 0
        if (p < n) {
            const int vid = view_id[0];              // VIEW_NUM == 1
            float dx = means[3 * p + 0] - scan_point[0];
            float dy = means[3 * p + 1] - scan_point[1];
            float dz = means[3 * p + 2] - scan_point[2];
            float r0 = sqrtf(fmaf(dx, dx, fmaf(dy, dy, dz * dz)));
            float sg = fmaxf(expf(scales[p]), 0.005f);   // max(mean(exp(scales)), BIN_RES/2)
            float inv_s = 1.0f / sg;
            float coeff = 1.0f / (1.0f + expf(-coeffs[p]));  // sigmoid
            float op  = opac[p + vid];
            float col = colours[p];
            float inten = (op * op) * (col * col);
            float ia = inten * 0.005f;                   // fold BIN_RES/2 and intensity
            v.x = r0;
            v.y = -0.5f * inv_s * inv_s * LOG2E;         // exp arg scale (log2e folded)
            v.z = ia * coeff * K_SQRT_HALF_PI * inv_s;   // pdf1 weight
            v.w = ia * (1.0f - coeff) * inv_s * inv_s;   // pdf2 weight
        }
        s_pt[t] = v;
    }
    __syncthreads();

    // --- each thread = one bin; sweep the chunk ---
    const float r = 0.005f * (float)(t + 1);   // T0/2 + BIN_RES/2 * (t+1)
    float acc = 0.f;
#pragma unroll 8
    for (int k = 0; k < CHUNK; ++k) {
        float4 v = s_pt[k];                    // broadcast ds_read_b128, conflict-free
        float diff = r - v.x;
        float e = FAST_EXP2(diff * diff * v.y);
        acc += __saturatef(e * fmaf(v.w, diff, v.z));
    }
    atomicAdd(&out[t], acc / (r * r));         // fold the /r_^DECAY (DECAY=2) per partial
}

extern "C" void kernel_launch(void* const* d_in, const int* in_sizes, int n_in,
                              void* d_out, int out_size, void* d_ws, size_t ws_size,
                              hipStream_t stream) {
    const float* means = (const float*)d_in[0];
    const float* scan  = (const float*)d_in[1];
    const float* col   = (const float*)d_in[2];
    const float* cf    = (const float*)d_in[3];
    const float* op    = (const float*)d_in[4];
    const float* sc    = (const float*)d_in[5];
    const int*   vid   = (const int*)d_in[6];
    float* out = (float*)d_out;

    const int n = in_sizes[2];                 // colours: NUM_POINTS elements
    hipMemsetAsync(d_out, 0, (size_t)out_size * sizeof(float), stream);
    const int blocks = (n + CHUNK - 1) / CHUNK;
    gauss_hist<<<blocks, NBINS, 0, stream>>>(means, scan, col, cf, op, sc, vid, out, n);
}